// Round 13
// baseline (2463.030 us; speedup 1.0000x reference)
//
#include <hip/hip_runtime.h>
#include <math.h>

typedef __attribute__((ext_vector_type(8))) _Float16 f16x8;
typedef __attribute__((ext_vector_type(4))) _Float16 f16x4;
typedef __attribute__((ext_vector_type(2))) __fp16 h16x2;
typedef __attribute__((ext_vector_type(4))) float f32x4;

#define TT 512
#define BB 256
#define HH 256
#define AA 8

// ws byte offsets
#define OFF_W1   0u           // 32 tiles  * 1024 B
#define OFF_WIH  32768u       // 384 tiles * 1024 B
#define OFF_WHH  425984u      // 384 tiles * 1024 B
#define OFF_H    819200u      // h_carry fp32 [256][256]
#define OFF_GI   1081344u     // gi fp16, per (t,bt16): 48*64*4*2 = 24576 B
#define GSTRIDE  393216       // gi bytes per timestep (16 bt16 tiles)

__device__ inline float fexp2(float x) { return __builtin_amdgcn_exp2f(x); }
__device__ inline float frcp(float x)  { return __builtin_amdgcn_rcpf(x); }
__device__ inline float fsigm(float x) { return frcp(1.f + fexp2(x * -1.4426950408889634f)); }
__device__ inline float ftanh_(float x){ return 1.f - 2.f * frcp(1.f + fexp2(x * 2.8853900817779268f)); }

// ---------------- phase 0: pack weights into fp16 MFMA B-fragments ----------
__global__ __launch_bounds__(256) void prepack(
    const float* __restrict__ W1, const float* __restrict__ Wih,
    const float* __restrict__ Whh, unsigned char* __restrict__ ws) {
  int gid = blockIdx.x * 256 + threadIdx.x;
  int wave = gid >> 6, l = gid & 63;
  const float* src; int K; int tix; size_t dst;
  if (wave < 32)       { src = W1;  K = 64;  tix = wave;       dst = OFF_W1; }
  else if (wave < 416) { src = Wih; K = 256; tix = wave - 32;  dst = OFF_WIH; }
  else                 { src = Whh; K = 256; tix = wave - 416; dst = OFF_WHH; }
  int ntJ = (K == 64) ? 16 : 48;
  int kt = tix / ntJ, jt = tix % ntJ;
  int j;
  if (K == 64) j = jt * 16 + (l & 15);
  else { int g = jt % 3, blk = jt / 3; j = g * 256 + blk * 16 + (l & 15); }
  int k = kt * 32 + (l >> 4) * 8;
  const float* p = src + (size_t)j * K + k;
  f16x8 frag;
#pragma unroll
  for (int e = 0; e < 8; ++e) frag[e] = (_Float16)p[e];
  *(f16x8*)(ws + dst + ((size_t)tix * 64 + l) * 16) = frag;
}

// ---------------- phase 1: gi = leakyrelu(x@W1^T+b1) @ W_ih^T + folded biases
// 2 timesteps per WG. Output layout unchanged.
__global__ __launch_bounds__(256) void gru_gi(
    const float* __restrict__ x, const float* __restrict__ b1,
    const float* __restrict__ b_ih, const float* __restrict__ b_hh,
    const unsigned char* __restrict__ wsro, unsigned char* __restrict__ giout,
    int t0) {
  __shared__ __align__(16) _Float16 sfh[2][16 * 256];
  int tid = threadIdx.x, w = tid >> 6, l = tid & 63;
  int tp = blockIdx.x >> 4, bt = blockIdx.x & 15;
  int row = l & 15, kg = l >> 4;

  const f16x8* pW1 = (const f16x8*)(wsro + OFF_W1);
#pragma unroll
  for (int tt = 0; tt < 2; ++tt) {
    int t = t0 + tp * 2 + tt;
    f32x4 sacc[4] = {{0.f,0.f,0.f,0.f},{0.f,0.f,0.f,0.f},{0.f,0.f,0.f,0.f},{0.f,0.f,0.f,0.f}};
    size_t xbase = ((size_t)t * BB + bt * 16 + row) * 64;
#pragma unroll
    for (int kt = 0; kt < 2; ++kt) {
      float4 p0 = *(const float4*)(x + xbase + kt * 32 + kg * 8);
      float4 p1 = *(const float4*)(x + xbase + kt * 32 + kg * 8 + 4);
      float xv[8] = {p0.x, p0.y, p0.z, p0.w, p1.x, p1.y, p1.z, p1.w};
      f16x8 xh;
#pragma unroll
      for (int e = 0; e < 8; ++e) xh[e] = (_Float16)xv[e];
#pragma unroll
      for (int jj = 0; jj < 4; ++jj) {
        f16x8 bw = pW1[(kt * 16 + w * 4 + jj) * 64 + l];
        sacc[jj] = __builtin_amdgcn_mfma_f32_16x16x32_f16(xh, bw, sacc[jj], 0, 0, 0);
      }
    }
#pragma unroll
    for (int jj = 0; jj < 4; ++jj) {
      int j = (w * 4 + jj) * 16 + row;
      float b1v = b1[j];
#pragma unroll
      for (int rg = 0; rg < 4; ++rg) {
        int rr = kg * 4 + rg;
        float v = sacc[jj][rg] + b1v;
        v = v >= 0.f ? v : 0.01f * v;
        int byt = (j * 2) ^ ((rr & 7) << 4);
        *(_Float16*)((char*)sfh[tt] + rr * 512 + byt) = (_Float16)v;
      }
    }
  }
  __syncthreads();

  f32x4 gacc[2][12];
#pragma unroll
  for (int tt = 0; tt < 2; ++tt)
#pragma unroll
    for (int jj = 0; jj < 12; ++jj) gacc[tt][jj] = (f32x4){0.f, 0.f, 0.f, 0.f};
  const f16x8* pWih = (const f16x8*)(wsro + OFF_WIH);
  for (int kt = 0; kt < 8; ++kt) {
    int rb = row * 512 + ((kt * 64 + kg * 16) ^ ((row & 7) << 4));
    f16x8 ah0 = *(const f16x8*)((const char*)sfh[0] + rb);
    f16x8 ah1 = *(const f16x8*)((const char*)sfh[1] + rb);
#pragma unroll
    for (int jj = 0; jj < 12; ++jj) {
      f16x8 bw = pWih[((size_t)(kt * 48 + w * 12 + jj)) * 64 + l];
      gacc[0][jj] = __builtin_amdgcn_mfma_f32_16x16x32_f16(ah0, bw, gacc[0][jj], 0, 0, 0);
      gacc[1][jj] = __builtin_amdgcn_mfma_f32_16x16x32_f16(ah1, bw, gacc[1][jj], 0, 0, 0);
    }
  }
  float biasv[12];
#pragma unroll
  for (int jj = 0; jj < 12; ++jj) {
    int jt = w * 12 + jj;
    int g = jt % 3, blk = jt / 3;
    int j = g * 256 + blk * 16 + row;
    biasv[jj] = b_ih[j] + (g < 2 ? b_hh[j] : 0.f);
  }
#pragma unroll
  for (int tt = 0; tt < 2; ++tt) {
    unsigned char* gbase =
        giout + (size_t)((tp * 2 + tt) * 16 + bt) * 24576 + (l >> 5) * 12288;
#pragma unroll
    for (int jj = 0; jj < 12; ++jj) {
      int jt = w * 12 + jj;
      f16x4 o;
#pragma unroll
      for (int rg = 0; rg < 4; ++rg) o[rg] = (_Float16)(gacc[tt][jj][rg] + biasv[jj]);
      *(f16x4*)(gbase + jt * 256 + (l & 31) * 8) = o;
    }
  }
}

// ---------------- phase 2: sequential GRU, 64 WGs (4 batch rows) x 512 thr ---
// M=4: halves per-CU update VALU/trans (the measured 88% issue saturation).
// A rows 4-15 duplicate rows 0-3 -> D rows are copies -> lane-local update,
// selecting acc[jj][copy?2+e:e]. whh pinned resident via opaque asm (+v) so
// the allocator cannot re-stream W_hh from L2 (the 128-VGPR heuristic).
__global__
__attribute__((amdgpu_flat_work_group_size(512, 512), amdgpu_waves_per_eu(2, 2)))
void gru_seq(
    const int* __restrict__ dones, const float* __restrict__ b_hh,
    const float* __restrict__ Wm, const float* __restrict__ bm,
    const float* __restrict__ Wsv, const float* __restrict__ bsv,
    const unsigned char* __restrict__ wsro, unsigned char* __restrict__ hcar,
    const unsigned char* __restrict__ gi, int t0, int tch,
    float* __restrict__ out) {
  __shared__ __align__(16) unsigned char hbuf[2][8192];  // K-major swizzled h (rows 4-15 dup)
  __shared__ unsigned char dnb[1024];                    // packed dones bytes [step][4 rows]
  int tid = threadIdx.x, w = tid >> 6, u = tid & 63;
  int bt4 = blockIdx.x, bt16 = bt4 >> 2, q = bt4 & 3;
  int row16 = u & 15, kg = u >> 4;                         // A-frag roles
  int col16 = u & 15, copy = (u >> 4) & 1, blk = u >> 5;   // update roles
  int c = (2 * w + blk) * 16 + col16;                      // owned h column

  // W_hh fragments: wave w owns jtn = 6w..6w+5
  f16x8 whh[6][8];
  const f16x8* pWhh = (const f16x8*)(wsro + OFF_WHH);
#pragma unroll
  for (int jj = 0; jj < 6; ++jj)
#pragma unroll
    for (int kt = 0; kt < 8; ++kt)
      whh[jj][kt] = pWhh[(size_t)(kt * 48 + 6 * w + jj) * 64 + u];
  // opaque pin: values now defined by asm -> cannot be rematerialized from L2
#pragma unroll
  for (int jj = 0; jj < 6; ++jj)
#pragma unroll
    for (int kt = 0; kt < 8; ++kt)
      asm volatile("" : "+v"(whh[jj][kt]));

  float bn = b_hh[512 + c];

  // loop-invariant LDS addresses
  int ab0 = (kg * 256 + row16 * 16) ^ (kg << 4);   // A-read base, even kt
  int ab1 = ab0 ^ 64;                              // odd kt
  int ku2 = c >> 3, e2 = c & 7;
  int wb = ku2 * 256 + e2 * 2;                     // write base (row added per-elem)
  int sw = (ku2 & 7) << 4;                         // write swizzle
  int rb0 = copy * 32;                             // row byte base: row = 2*copy + e
  const char* hro = (const char*)hbuf;

  // h_old init + write rows (and dups rows+4k) into hbuf[0]
  float h_old[2];
#pragma unroll
  for (int e = 0; e < 2; ++e) {
    float hv = ((const float*)hcar)[(bt4 * 4 + 2 * copy + e) * 256 + c];
    h_old[e] = hv;
#pragma unroll
    for (int d = 0; d < 4; ++d)
      *(_Float16*)((char*)hbuf + ((wb + rb0 + e * 16 + d * 64) ^ sw)) = (_Float16)hv;
  }

  // preload ALL (shifted) dones for this chunk as bytes: dnb[s*4 + r]
#pragma unroll
  for (int ii = 0; ii < 2; ++ii) {
    int ix = ii * 512 + tid;
    if (ix < tch * 4) {
      int ti = t0 + (ix >> 2) + 1;
      dnb[ix] = (ti < TT) ? (unsigned char)(dones[ti * BB + bt4 * 4 + (ix & 3)] != 0) : (unsigned char)0;
    }
  }

  // gi per-thread pointer: quarter q -> half file q>>1, row-group q&1, rows 2copy+e
  const unsigned char* gpt = gi + (size_t)bt16 * 24576 + (q >> 1) * 12288 +
                             (2 * w + blk) * 768 + ((q & 1) * 16 + col16) * 8 + copy * 4;
  unsigned int gA[3], gB[3];
#pragma unroll
  for (int g = 0; g < 3; ++g) gA[g] = *(const unsigned int*)(gpt + g * 256);

  asm volatile("s_waitcnt lgkmcnt(0)" ::: "memory");
  __builtin_amdgcn_s_barrier();

#define STEP(TL, P, GC, GN)                                                     \
  {                                                                             \
    int tn = (TL) + 1 < tch ? (TL) + 1 : tch - 1;                               \
    const unsigned char* gpn = gpt + (size_t)tn * GSTRIDE;                      \
    GN[0] = *(const unsigned int*)(gpn);                                        \
    GN[1] = *(const unsigned int*)(gpn + 256);                                  \
    GN[2] = *(const unsigned int*)(gpn + 512);                                  \
    f32x4 acc[6];                                                               \
    _Pragma("unroll") for (int jj = 0; jj < 6; ++jj)                            \
        acc[jj] = (f32x4){0.f, 0.f, 0.f, 0.f};                                  \
    _Pragma("unroll") for (int kt = 0; kt < 8; ++kt) {                          \
      f16x8 ah = *(const f16x8*)(hro + (P) * 8192 + kt * 1024 +                 \
                                 ((kt & 1) ? ab1 : ab0));                       \
      _Pragma("unroll") for (int jj = 0; jj < 6; ++jj)                          \
        acc[jj] = __builtin_amdgcn_mfma_f32_16x16x32_f16(ah, whh[jj][kt],       \
                                                         acc[jj], 0, 0, 0);     \
    }                                                                           \
    int dn2 = *(const unsigned short*)(dnb + (TL) * 4 + copy * 2);              \
    char* hw = (char*)hbuf + ((P) ^ 1) * 8192;                                  \
    _Pragma("unroll") for (int e = 0; e < 2; ++e) {                             \
      float avr = copy ? acc[blk * 3 + 0][2 + e] : acc[blk * 3 + 0][e];         \
      float avz = copy ? acc[blk * 3 + 1][2 + e] : acc[blk * 3 + 1][e];         \
      float avn = copy ? acc[blk * 3 + 2][2 + e] : acc[blk * 3 + 2][e];         \
      float gr = (float)__builtin_bit_cast(h16x2, GC[0])[e];                    \
      float gz = (float)__builtin_bit_cast(h16x2, GC[1])[e];                    \
      float gn = (float)__builtin_bit_cast(h16x2, GC[2])[e];                    \
      float rs = fsigm(gr + avr);                                               \
      float zs = fsigm(gz + avz);                                               \
      float ng = ftanh_(gn + rs * (avn + bn));                                  \
      float hn = ng + zs * (h_old[e] - ng);                                     \
      hn = ((dn2 >> (e * 8)) & 0xff) ? 0.f : hn;                                \
      h_old[e] = hn;                                                            \
      _Float16 hh = (_Float16)hn;                                               \
      _Pragma("unroll") for (int d = 0; d < 4; ++d)                             \
        *(_Float16*)(hw + ((wb + rb0 + e * 16 + d * 64) ^ sw)) = hh;            \
    }                                                                           \
    asm volatile("s_waitcnt lgkmcnt(0)" ::: "memory");                          \
    __builtin_amdgcn_s_barrier();                                               \
  }

  for (int tl = 0; tl < tch; tl += 2) {
    STEP(tl, 0, gA, gB);
    STEP(tl + 1, 1, gB, gA);
  }
#undef STEP

  // carry h to next chunk
#pragma unroll
  for (int e = 0; e < 2; ++e)
    ((float*)hcar)[(bt4 * 4 + 2 * copy + e) * 256 + c] = h_old[e];

  if (t0 + tch == TT) {
#pragma unroll
    for (int e = 0; e < 2; ++e)
      out[2 * BB * AA + (bt4 * 4 + 2 * copy + e) * 256 + c] = h_old[e];
    // heads on h_final (rows 0-3 real; final parity 0 after even tch)
    if (tid < 64) {
      int r2 = tid >> 4, a = (tid >> 1) & 7, hd = tid & 1;
      const float* W = hd ? Wsv : Wm;
      float acc2 = 0.f;
      for (int k = 0; k < 256; k += 8) {
        int ku = k >> 3;
        f16x8 vh = *(const f16x8*)(hro + ((ku * 256 + r2 * 16) ^ ((ku & 7) << 4)));
#pragma unroll
        for (int e = 0; e < 8; ++e)
          acc2 += (float)vh[e] * W[a * 256 + k + e];
      }
      int b = bt4 * 4 + r2;
      if (hd == 0) {
        out[b * AA + a] = tanhf(acc2 + bm[a]);
      } else {
        float v = acc2 + bsv[a];
        float sp = fmaxf(v, 0.f) + log1pf(expf(-fabsf(v)));
        out[BB * AA + b * AA + a] = fmaxf(sp, 1e-5f);
      }
    }
  }
}

extern "C" void kernel_launch(void* const* d_in, const int* in_sizes, int n_in,
                              void* d_out, int out_size, void* d_ws, size_t ws_size,
                              hipStream_t stream) {
  const float* x    = (const float*)d_in[0];
  const int*   dn   = (const int*)  d_in[1];
  const float* W1   = (const float*)d_in[2];
  const float* b1   = (const float*)d_in[3];
  const float* W_ih = (const float*)d_in[4];
  const float* W_hh = (const float*)d_in[5];
  const float* b_ih = (const float*)d_in[6];
  const float* b_hh = (const float*)d_in[7];
  const float* Wm   = (const float*)d_in[8];
  const float* bm   = (const float*)d_in[9];
  const float* Wsv  = (const float*)d_in[10];
  const float* bs   = (const float*)d_in[11];
  float* out = (float*)d_out;
  unsigned char* ws = (unsigned char*)d_ws;

  // largest chunk whose gi fits in ws; clamp to 256 (dnb sizing, even count)
  int tch = 256;
  while (tch > 1 && (size_t)OFF_GI + (size_t)tch * 16 * 24576 > ws_size) tch >>= 1;

  prepack<<<200, 256, 0, stream>>>(W1, W_ih, W_hh, ws);
  (void)hipMemsetAsync(ws + OFF_H, 0, 262144, stream);
  for (int t0 = 0; t0 < TT; t0 += tch) {
    gru_gi<<<dim3((tch / 2) * 16), 256, 0, stream>>>(x, b1, b_ih, b_hh, ws, ws + OFF_GI, t0);
    gru_seq<<<64, 512, 0, stream>>>(dn, b_hh, Wm, bm, Wsv, bs, ws, ws + OFF_H,
                                    ws + OFF_GI, t0, tch, out);
  }
}

// Round 17
// 791.463 us; speedup vs baseline: 3.1120x; 3.1120x over previous
//
#include <hip/hip_runtime.h>
#include <math.h>

typedef __attribute__((ext_vector_type(8))) _Float16 f16x8;
typedef __attribute__((ext_vector_type(4))) _Float16 f16x4;
typedef __attribute__((ext_vector_type(4))) float f32x4;

#define TT 512
#define BB 256
#define HH 256
#define AA 8

// ws byte offsets
#define OFF_W1   0u           // 32 tiles  * 1024 B
#define OFF_WIH  32768u       // 384 tiles * 1024 B
#define OFF_WHH  425984u      // 384 tiles * 1024 B
#define OFF_H    819200u      // h_carry fp32 [256][256]
#define OFF_GI   1081344u     // gi fp16, per (t,bt16): 48*64*4*2 = 24576 B
#define GSTRIDE  393216       // gi bytes per timestep (16 bt16 tiles)

__device__ inline float fexp2(float x) { return __builtin_amdgcn_exp2f(x); }
__device__ inline float frcp(float x)  { return __builtin_amdgcn_rcpf(x); }
__device__ inline float fsigm(float x) { return frcp(1.f + fexp2(x * -1.4426950408889634f)); }
__device__ inline float ftanh_(float x){ return 1.f - 2.f * frcp(1.f + fexp2(x * 2.8853900817779268f)); }

// ---------------- phase 0: pack weights into fp16 MFMA B-fragments ----------
__global__ __launch_bounds__(256) void prepack(
    const float* __restrict__ W1, const float* __restrict__ Wih,
    const float* __restrict__ Whh, unsigned char* __restrict__ ws) {
  int gid = blockIdx.x * 256 + threadIdx.x;
  int wave = gid >> 6, l = gid & 63;
  const float* src; int K; int tix; size_t dst;
  if (wave < 32)       { src = W1;  K = 64;  tix = wave;       dst = OFF_W1; }
  else if (wave < 416) { src = Wih; K = 256; tix = wave - 32;  dst = OFF_WIH; }
  else                 { src = Whh; K = 256; tix = wave - 416; dst = OFF_WHH; }
  int ntJ = (K == 64) ? 16 : 48;
  int kt = tix / ntJ, jt = tix % ntJ;
  int j;
  if (K == 64) j = jt * 16 + (l & 15);
  else { int g = jt % 3, blk = jt / 3; j = g * 256 + blk * 16 + (l & 15); }
  int k = kt * 32 + (l >> 4) * 8;
  const float* p = src + (size_t)j * K + k;
  f16x8 frag;
#pragma unroll
  for (int e = 0; e < 8; ++e) frag[e] = (_Float16)p[e];
  *(f16x8*)(ws + dst + ((size_t)tix * 64 + l) * 16) = frag;
}

// ---------------- phase 1: gi = leakyrelu(x@W1^T+b1) @ W_ih^T + folded biases
// 2 timesteps per WG (halves W_ih L2 streaming).
__global__ __launch_bounds__(256) void gru_gi(
    const float* __restrict__ x, const float* __restrict__ b1,
    const float* __restrict__ b_ih, const float* __restrict__ b_hh,
    const unsigned char* __restrict__ wsro, unsigned char* __restrict__ giout,
    int t0) {
  __shared__ __align__(16) _Float16 sfh[2][16 * 256];
  int tid = threadIdx.x, w = tid >> 6, l = tid & 63;
  int tp = blockIdx.x >> 4, bt = blockIdx.x & 15;
  int row = l & 15, kg = l >> 4;

  const f16x8* pW1 = (const f16x8*)(wsro + OFF_W1);
#pragma unroll
  for (int tt = 0; tt < 2; ++tt) {
    int t = t0 + tp * 2 + tt;
    f32x4 sacc[4] = {{0.f,0.f,0.f,0.f},{0.f,0.f,0.f,0.f},{0.f,0.f,0.f,0.f},{0.f,0.f,0.f,0.f}};
    size_t xbase = ((size_t)t * BB + bt * 16 + row) * 64;
#pragma unroll
    for (int kt = 0; kt < 2; ++kt) {
      float4 p0 = *(const float4*)(x + xbase + kt * 32 + kg * 8);
      float4 p1 = *(const float4*)(x + xbase + kt * 32 + kg * 8 + 4);
      float xv[8] = {p0.x, p0.y, p0.z, p0.w, p1.x, p1.y, p1.z, p1.w};
      f16x8 xh;
#pragma unroll
      for (int e = 0; e < 8; ++e) xh[e] = (_Float16)xv[e];
#pragma unroll
      for (int jj = 0; jj < 4; ++jj) {
        f16x8 bw = pW1[(kt * 16 + w * 4 + jj) * 64 + l];
        sacc[jj] = __builtin_amdgcn_mfma_f32_16x16x32_f16(xh, bw, sacc[jj], 0, 0, 0);
      }
    }
#pragma unroll
    for (int jj = 0; jj < 4; ++jj) {
      int j = (w * 4 + jj) * 16 + row;
      float b1v = b1[j];
#pragma unroll
      for (int rg = 0; rg < 4; ++rg) {
        int rr = kg * 4 + rg;
        float v = sacc[jj][rg] + b1v;
        v = v >= 0.f ? v : 0.01f * v;
        int byt = (j * 2) ^ ((rr & 7) << 4);
        *(_Float16*)((char*)sfh[tt] + rr * 512 + byt) = (_Float16)v;
      }
    }
  }
  __syncthreads();

  f32x4 gacc[2][12];
#pragma unroll
  for (int tt = 0; tt < 2; ++tt)
#pragma unroll
    for (int jj = 0; jj < 12; ++jj) gacc[tt][jj] = (f32x4){0.f, 0.f, 0.f, 0.f};
  const f16x8* pWih = (const f16x8*)(wsro + OFF_WIH);
  for (int kt = 0; kt < 8; ++kt) {
    int rb = row * 512 + ((kt * 64 + kg * 16) ^ ((row & 7) << 4));
    f16x8 ah0 = *(const f16x8*)((const char*)sfh[0] + rb);
    f16x8 ah1 = *(const f16x8*)((const char*)sfh[1] + rb);
#pragma unroll
    for (int jj = 0; jj < 12; ++jj) {
      f16x8 bw = pWih[((size_t)(kt * 48 + w * 12 + jj)) * 64 + l];
      gacc[0][jj] = __builtin_amdgcn_mfma_f32_16x16x32_f16(ah0, bw, gacc[0][jj], 0, 0, 0);
      gacc[1][jj] = __builtin_amdgcn_mfma_f32_16x16x32_f16(ah1, bw, gacc[1][jj], 0, 0, 0);
    }
  }
  float biasv[12];
#pragma unroll
  for (int jj = 0; jj < 12; ++jj) {
    int jt = w * 12 + jj;
    int g = jt % 3, blk = jt / 3;
    int j = g * 256 + blk * 16 + row;
    biasv[jj] = b_ih[j] + (g < 2 ? b_hh[j] : 0.f);
  }
#pragma unroll
  for (int tt = 0; tt < 2; ++tt) {
    unsigned char* gbase =
        giout + (size_t)((tp * 2 + tt) * 16 + bt) * 24576 + (l >> 5) * 12288;
#pragma unroll
    for (int jj = 0; jj < 12; ++jj) {
      int jt = w * 12 + jj;
      f16x4 o;
#pragma unroll
      for (int rg = 0; rg < 4; ++rg) o[rg] = (_Float16)(gacc[tt][jj][rg] + biasv[jj]);
      *(f16x4*)(gbase + jt * 256 + (l & 31) * 8) = o;
    }
  }
}

// ---------------- phase 2: sequential GRU, 32 WGs (8 batch rows) x 512 thr ---
// W_hh register-resident; gi direct global->reg 1-step prefetch; K-major
// swizzled h LDS; broadcast-paired A-reads. Key insight: with A rows 8-15
// aliasing rows 0-7, D rows 8-15 (lanes 32-63) are bit-exact copies of rows
// 0-7 for ALL acc tiles -> lanes >=32 already hold block-1 values for their
// update rows. No compaction shuffle needed at all.
__global__ __launch_bounds__(512, 2) void gru_seq(
    const int* __restrict__ dones, const float* __restrict__ b_hh,
    const float* __restrict__ Wm, const float* __restrict__ bm,
    const float* __restrict__ Wsv, const float* __restrict__ bsv,
    const unsigned char* __restrict__ wsro, unsigned char* __restrict__ hcar,
    const unsigned char* __restrict__ gi, int t0, int tch,
    float* __restrict__ out) {
  __shared__ __align__(16) unsigned char hbuf[2][8192];  // K-major swizzled h
  __shared__ unsigned char dnb[2048];                    // packed dones bytes
  int tid = threadIdx.x, w = tid >> 6, u = tid & 63;
  int bt8 = blockIdx.x, bt16 = bt8 >> 1, half = bt8 & 1;
  int kg = u >> 4;                                         // A-frag k-group
  int col16 = u & 15, rgrp = (u >> 4) & 1, blk = u >> 5;   // update roles
  int c = (2 * w + blk) * 16 + col16;                      // owned h column

  // W_hh fragments: wave w owns jtn = 6w..6w+5 (blocks {2w,2w+1} x gates r,z,n)
  f16x8 whh[6][8];
  const f16x8* pWhh = (const f16x8*)(wsro + OFF_WHH);
#pragma unroll
  for (int jj = 0; jj < 6; ++jj)
#pragma unroll
    for (int kt = 0; kt < 8; ++kt)
      whh[jj][kt] = pWhh[(size_t)(kt * 48 + 6 * w + jj) * 64 + u];

  float bn = b_hh[512 + c];

  // loop-invariant LDS addresses; rows 8-15 alias rows 0-7 (broadcast pairs;
  // D rows 8-15 = exact copies of rows 0-7, consumed in-lane by the update)
  int ab0 = (kg * 256 + (u & 7) * 16) ^ (kg << 4);   // A-read base, even kt
  int ab1 = ab0 ^ 64;                                // odd kt
  int ku2 = c >> 3, e2 = c & 7;
  int wbase = (ku2 * 256 + rgrp * 64 + e2 * 2) ^ ((ku2 & 7) << 4);
  const char* hro = (const char*)hbuf;

  // zero rows 8-15 region (defensive; A-reads no longer touch it)
  {
    int buf = tid >> 8, r = tid & 255;
    f16x8 z;
#pragma unroll
    for (int e = 0; e < 8; ++e) z[e] = (_Float16)0.f;
    *(f16x8*)((char*)hbuf + buf * 8192 + (r >> 3) * 256 + 128 + (r & 7) * 16) = z;
  }

  // h_old init + hbuf[0] rows 0..7
  float h_old[4];
#pragma unroll
  for (int rg = 0; rg < 4; ++rg) {
    float hv = ((const float*)hcar)[(bt8 * 8 + rgrp * 4 + rg) * 256 + c];
    h_old[rg] = hv;
    *(_Float16*)((char*)hbuf + (wbase ^ (rg << 4))) = (_Float16)hv;
  }

  // preload ALL (shifted) dones for this chunk as bytes
#pragma unroll
  for (int ii = 0; ii < 4; ++ii) {
    int ix = ii * 512 + tid;
    if (ix < tch * 8) {
      int ti = t0 + (ix >> 3) + 1;
      dnb[ix] = (ti < TT) ? (unsigned char)(dones[ti * BB + bt8 * 8 + (ix & 7)] != 0) : (unsigned char)0;
    }
  }

  // gi per-thread pointer (layout matches producer exactly)
  const unsigned char* gpt = gi + (size_t)bt16 * 24576 + half * 12288 +
                             (2 * w + blk) * 768 + (u & 31) * 8;
  f16x4 gA[3], gB[3];
#pragma unroll
  for (int g = 0; g < 3; ++g) gA[g] = *(const f16x4*)(gpt + g * 256);

  asm volatile("s_waitcnt lgkmcnt(0)" ::: "memory");
  __builtin_amdgcn_s_barrier();

#define STEP(TL, P, GC, GN)                                                     \
  {                                                                             \
    int tn = (TL) + 1 < tch ? (TL) + 1 : tch - 1;                               \
    const unsigned char* gpn = gpt + (size_t)tn * GSTRIDE;                      \
    GN[0] = *(const f16x4*)(gpn);                                               \
    GN[1] = *(const f16x4*)(gpn + 256);                                         \
    GN[2] = *(const f16x4*)(gpn + 512);                                         \
    f32x4 acc[6];                                                               \
    _Pragma("unroll") for (int jj = 0; jj < 6; ++jj)                            \
        acc[jj] = (f32x4){0.f, 0.f, 0.f, 0.f};                                  \
    _Pragma("unroll") for (int kt = 0; kt < 8; ++kt) {                          \
      f16x8 ah = *(const f16x8*)(hro + (P) * 8192 + kt * 1024 +                 \
                                 ((kt & 1) ? ab1 : ab0));                       \
      _Pragma("unroll") for (int jj = 0; jj < 6; ++jj)                          \
        acc[jj] = __builtin_amdgcn_mfma_f32_16x16x32_f16(ah, whh[jj][kt],       \
                                                         acc[jj], 0, 0, 0);     \
    }                                                                           \
    int dn4 = *(const int*)(dnb + (TL) * 8 + rgrp * 4);                         \
    char* hw = (char*)hbuf + ((P) ^ 1) * 8192;                                  \
    _Pragma("unroll") for (int rg = 0; rg < 4; ++rg) {                          \
      float avr = blk ? acc[3][rg] : acc[0][rg];                                \
      float avz = blk ? acc[4][rg] : acc[1][rg];                                \
      float avn = blk ? acc[5][rg] : acc[2][rg];                                \
      float rs = fsigm((float)GC[0][rg] + avr);                                 \
      float zs = fsigm((float)GC[1][rg] + avz);                                 \
      float ng = ftanh_((float)GC[2][rg] + rs * (avn + bn));                    \
      float hn = ng + zs * (h_old[rg] - ng);                                    \
      hn = ((dn4 >> (rg * 8)) & 0xff) ? 0.f : hn;                               \
      h_old[rg] = hn;                                                           \
      *(_Float16*)(hw + (wbase ^ (rg << 4))) = (_Float16)hn;                    \
    }                                                                           \
    asm volatile("s_waitcnt lgkmcnt(0)" ::: "memory");                          \
    __builtin_amdgcn_s_barrier();                                               \
  }

  for (int tl = 0; tl < tch; tl += 2) {
    STEP(tl, 0, gA, gB);
    STEP(tl + 1, 1, gB, gA);
  }
#undef STEP

  // carry h to next chunk
#pragma unroll
  for (int rg = 0; rg < 4; ++rg)
    ((float*)hcar)[(bt8 * 8 + rgrp * 4 + rg) * 256 + c] = h_old[rg];

  if (t0 + tch == TT) {
#pragma unroll
    for (int rg = 0; rg < 4; ++rg)
      out[2 * BB * AA + (bt8 * 8 + rgrp * 4 + rg) * 256 + c] = h_old[rg];
    // heads on h_final (read fp16 h from LDS buffer 0 — final parity after even tch)
    if (tid < 128) {
      int r2 = tid >> 4, a = (tid >> 1) & 7, hd = tid & 1;
      const float* W = hd ? Wsv : Wm;
      float acc2 = 0.f;
      for (int k = 0; k < 256; k += 8) {
        int ku = k >> 3;
        f16x8 vh = *(const f16x8*)(hro + ((ku * 256 + r2 * 16) ^ ((ku & 7) << 4)));
#pragma unroll
        for (int e = 0; e < 8; ++e)
          acc2 += (float)vh[e] * W[a * 256 + k + e];
      }
      int b = bt8 * 8 + r2;
      if (hd == 0) {
        out[b * AA + a] = tanhf(acc2 + bm[a]);
      } else {
        float v = acc2 + bsv[a];
        float sp = fmaxf(v, 0.f) + log1pf(expf(-fabsf(v)));
        out[BB * AA + b * AA + a] = fmaxf(sp, 1e-5f);
      }
    }
  }
}

extern "C" void kernel_launch(void* const* d_in, const int* in_sizes, int n_in,
                              void* d_out, int out_size, void* d_ws, size_t ws_size,
                              hipStream_t stream) {
  const float* x    = (const float*)d_in[0];
  const int*   dn   = (const int*)  d_in[1];
  const float* W1   = (const float*)d_in[2];
  const float* b1   = (const float*)d_in[3];
  const float* W_ih = (const float*)d_in[4];
  const float* W_hh = (const float*)d_in[5];
  const float* b_ih = (const float*)d_in[6];
  const float* b_hh = (const float*)d_in[7];
  const float* Wm   = (const float*)d_in[8];
  const float* bm   = (const float*)d_in[9];
  const float* Wsv  = (const float*)d_in[10];
  const float* bs   = (const float*)d_in[11];
  float* out = (float*)d_out;
  unsigned char* ws = (unsigned char*)d_ws;

  // largest chunk whose gi fits in ws; clamp to 256 (dnb/LDS sizing, even count)
  int tch = 256;
  while (tch > 1 && (size_t)OFF_GI + (size_t)tch * 16 * 24576 > ws_size) tch >>= 1;

  prepack<<<200, 256, 0, stream>>>(W1, W_ih, W_hh, ws);
  (void)hipMemsetAsync(ws + OFF_H, 0, 262144, stream);
  for (int t0 = 0; t0 < TT; t0 += tch) {
    gru_gi<<<dim3((tch / 2) * 16), 256, 0, stream>>>(x, b1, b_ih, b_hh, ws, ws + OFF_GI, t0);
    gru_seq<<<32, 512, 0, stream>>>(dn, b_hh, Wm, bm, Wsv, bs, ws, ws + OFF_H,
                                    ws + OFF_GI, t0, tch, out);
  }
}

// Round 18
// 660.545 us; speedup vs baseline: 3.7288x; 1.1982x over previous
//
#include <hip/hip_runtime.h>
#include <math.h>

typedef __attribute__((ext_vector_type(8))) _Float16 f16x8;
typedef __attribute__((ext_vector_type(4))) _Float16 f16x4;
typedef __attribute__((ext_vector_type(4))) float f32x4;

#define TT 512
#define BB 256
#define HH 256
#define AA 8

// ws byte offsets
#define OFF_W1   0u           // 32 tiles  * 1024 B
#define OFF_WIH  32768u       // 384 tiles * 1024 B
#define OFF_WHH  425984u      // 384 tiles * 1024 B
#define OFF_H    819200u      // h_carry fp32 [256][256]
#define OFF_GI   1081344u     // gi fp16 double-buffer starts here
#define GSTRIDE  393216       // gi bytes per timestep within a buffer

__device__ inline float fexp2(float x) { return __builtin_amdgcn_exp2f(x); }
__device__ inline float frcp(float x)  { return __builtin_amdgcn_rcpf(x); }
__device__ inline float fsigm(float x) { return frcp(1.f + fexp2(x * -1.4426950408889634f)); }
__device__ inline float ftanh_(float x){ return 1.f - 2.f * frcp(1.f + fexp2(x * 2.8853900817779268f)); }

// ---------------- phase 0: pack weights into fp16 MFMA B-fragments ----------
__global__ __launch_bounds__(256) void prepack(
    const float* __restrict__ W1, const float* __restrict__ Wih,
    const float* __restrict__ Whh, unsigned char* __restrict__ ws) {
  int gid = blockIdx.x * 256 + threadIdx.x;
  int wave = gid >> 6, l = gid & 63;
  const float* src; int K; int tix; size_t dst;
  if (wave < 32)       { src = W1;  K = 64;  tix = wave;       dst = OFF_W1; }
  else if (wave < 416) { src = Wih; K = 256; tix = wave - 32;  dst = OFF_WIH; }
  else                 { src = Whh; K = 256; tix = wave - 416; dst = OFF_WHH; }
  int ntJ = (K == 64) ? 16 : 48;
  int kt = tix / ntJ, jt = tix % ntJ;
  int j;
  if (K == 64) j = jt * 16 + (l & 15);
  else { int g = jt % 3, blk = jt / 3; j = g * 256 + blk * 16 + (l & 15); }
  int k = kt * 32 + (l >> 4) * 8;
  const float* p = src + (size_t)j * K + k;
  f16x8 frag;
#pragma unroll
  for (int e = 0; e < 8; ++e) frag[e] = (_Float16)p[e];
  *(f16x8*)(ws + dst + ((size_t)tix * 64 + l) * 16) = frag;
}

// ---------------- gi body (device fn): one (tp,bt) pair, 2 timesteps, 4 waves
// tid in [0,256); caller handles the mid-phase barrier via flag.
__device__ __forceinline__ void gi_sf_phase(
    const float* __restrict__ x, const float* __restrict__ b1,
    const unsigned char* __restrict__ wsro, _Float16* sfh0, _Float16* sfh1,
    int t0, int tp, int bt, int tid) {
  int w = tid >> 6, l = tid & 63;
  int row = l & 15, kg = l >> 4;
  const f16x8* pW1 = (const f16x8*)(wsro + OFF_W1);
  _Float16* sfh[2] = {sfh0, sfh1};
#pragma unroll
  for (int tt = 0; tt < 2; ++tt) {
    int t = t0 + tp * 2 + tt;
    f32x4 sacc[4] = {{0.f,0.f,0.f,0.f},{0.f,0.f,0.f,0.f},{0.f,0.f,0.f,0.f},{0.f,0.f,0.f,0.f}};
    size_t xbase = ((size_t)t * BB + bt * 16 + row) * 64;
#pragma unroll
    for (int kt = 0; kt < 2; ++kt) {
      float4 p0 = *(const float4*)(x + xbase + kt * 32 + kg * 8);
      float4 p1 = *(const float4*)(x + xbase + kt * 32 + kg * 8 + 4);
      float xv[8] = {p0.x, p0.y, p0.z, p0.w, p1.x, p1.y, p1.z, p1.w};
      f16x8 xh;
#pragma unroll
      for (int e = 0; e < 8; ++e) xh[e] = (_Float16)xv[e];
#pragma unroll
      for (int jj = 0; jj < 4; ++jj) {
        f16x8 bw = pW1[(kt * 16 + w * 4 + jj) * 64 + l];
        sacc[jj] = __builtin_amdgcn_mfma_f32_16x16x32_f16(xh, bw, sacc[jj], 0, 0, 0);
      }
    }
#pragma unroll
    for (int jj = 0; jj < 4; ++jj) {
      int j = (w * 4 + jj) * 16 + row;
      float b1v = b1[j];
#pragma unroll
      for (int rg = 0; rg < 4; ++rg) {
        int rr = kg * 4 + rg;
        float v = sacc[jj][rg] + b1v;
        v = v >= 0.f ? v : 0.01f * v;
        int byt = (j * 2) ^ ((rr & 7) << 4);
        *(_Float16*)((char*)sfh[tt] + rr * 512 + byt) = (_Float16)v;
      }
    }
  }
}

__device__ __forceinline__ void gi_gemm_phase(
    const float* __restrict__ b_ih, const float* __restrict__ b_hh,
    const unsigned char* __restrict__ wsro, const _Float16* sfh0,
    const _Float16* sfh1, unsigned char* __restrict__ giout,
    int tp, int bt, int tid) {
  int w = tid >> 6, l = tid & 63;
  int row = l & 15, kg = l >> 4;
  f32x4 gacc[2][12];
#pragma unroll
  for (int tt = 0; tt < 2; ++tt)
#pragma unroll
    for (int jj = 0; jj < 12; ++jj) gacc[tt][jj] = (f32x4){0.f, 0.f, 0.f, 0.f};
  const f16x8* pWih = (const f16x8*)(wsro + OFF_WIH);
  for (int kt = 0; kt < 8; ++kt) {
    int rb = row * 512 + ((kt * 64 + kg * 16) ^ ((row & 7) << 4));
    f16x8 ah0 = *(const f16x8*)((const char*)sfh0 + rb);
    f16x8 ah1 = *(const f16x8*)((const char*)sfh1 + rb);
#pragma unroll
    for (int jj = 0; jj < 12; ++jj) {
      f16x8 bw = pWih[((size_t)(kt * 48 + w * 12 + jj)) * 64 + l];
      gacc[0][jj] = __builtin_amdgcn_mfma_f32_16x16x32_f16(ah0, bw, gacc[0][jj], 0, 0, 0);
      gacc[1][jj] = __builtin_amdgcn_mfma_f32_16x16x32_f16(ah1, bw, gacc[1][jj], 0, 0, 0);
    }
  }
  float biasv[12];
#pragma unroll
  for (int jj = 0; jj < 12; ++jj) {
    int jt = w * 12 + jj;
    int g = jt % 3, blk = jt / 3;
    int j = g * 256 + blk * 16 + row;
    biasv[jj] = b_ih[j] + (g < 2 ? b_hh[j] : 0.f);
  }
#pragma unroll
  for (int tt = 0; tt < 2; ++tt) {
    unsigned char* gbase =
        giout + (size_t)((tp * 2 + tt) * 16 + bt) * 24576 + (l >> 5) * 12288;
#pragma unroll
    for (int jj = 0; jj < 12; ++jj) {
      int jt = w * 12 + jj;
      f16x4 o;
#pragma unroll
      for (int rg = 0; rg < 4; ++rg) o[rg] = (_Float16)(gacc[tt][jj][rg] + biasv[jj]);
      *(f16x4*)(gbase + jt * 256 + (l & 31) * 8) = o;
    }
  }
}

// ---------------- prologue gi kernel (chunk 0), 256 threads -----------------
__global__ __launch_bounds__(256) void gru_gi(
    const float* __restrict__ x, const float* __restrict__ b1,
    const float* __restrict__ b_ih, const float* __restrict__ b_hh,
    const unsigned char* __restrict__ wsro, unsigned char* __restrict__ giout,
    int t0) {
  __shared__ __align__(16) _Float16 sfh[2][16 * 256];
  int tid = threadIdx.x;
  int tp = blockIdx.x >> 4, bt = blockIdx.x & 15;
  gi_sf_phase(x, b1, wsro, sfh[0], sfh[1], t0, tp, bt, tid);
  __syncthreads();
  gi_gemm_phase(b_ih, b_hh, wsro, sfh[0], sfh[1], giout, tp, bt, tid);
}

// ---------------- fused: blocks 0-31 = seq(chunk i); blocks 32+ = gi(chunk i+1)
// seq path verbatim r10/r17 (791 us config). gi path: tid<256 active, single
// block-wide barrier between its phases (idle waves 4-7 just join barriers).
__global__ __launch_bounds__(512, 2) void gru_fused(
    const float* __restrict__ x,
    const int* __restrict__ dones, const float* __restrict__ b1,
    const float* __restrict__ b_ih, const float* __restrict__ b_hh,
    const float* __restrict__ Wm, const float* __restrict__ bm,
    const float* __restrict__ Wsv, const float* __restrict__ bsv,
    const unsigned char* __restrict__ wsro, unsigned char* __restrict__ hcar,
    const unsigned char* __restrict__ gi, unsigned char* __restrict__ giout,
    int t0, int tch, int gi_t0,
    float* __restrict__ out) {
  int tid = threadIdx.x;

  if (blockIdx.x >= 32) {
    // ---- gi path for next chunk
    __shared__ __align__(16) _Float16 sfh[2][16 * 256];
    int bg = blockIdx.x - 32;
    int tp = bg >> 4, bt = bg & 15;
    if (tid < 256)
      gi_sf_phase(x, b1, wsro, sfh[0], sfh[1], gi_t0, tp, bt, tid);
    __syncthreads();
    if (tid < 256)
      gi_gemm_phase(b_ih, b_hh, wsro, sfh[0], sfh[1], giout, tp, bt, tid);
    return;
  }

  // ---- seq path (verbatim r17)
  __shared__ __align__(16) unsigned char hbuf[2][8192];  // K-major swizzled h
  __shared__ unsigned char dnb[2048];                    // packed dones bytes
  int w = tid >> 6, u = tid & 63;
  int bt8 = blockIdx.x, bt16 = bt8 >> 1, half = bt8 & 1;
  int kg = u >> 4;                                         // A-frag k-group
  int col16 = u & 15, rgrp = (u >> 4) & 1, blk = u >> 5;   // update roles
  int c = (2 * w + blk) * 16 + col16;                      // owned h column

  f16x8 whh[6][8];
  const f16x8* pWhh = (const f16x8*)(wsro + OFF_WHH);
#pragma unroll
  for (int jj = 0; jj < 6; ++jj)
#pragma unroll
    for (int kt = 0; kt < 8; ++kt)
      whh[jj][kt] = pWhh[(size_t)(kt * 48 + 6 * w + jj) * 64 + u];

  float bn = b_hh[512 + c];

  int ab0 = (kg * 256 + (u & 7) * 16) ^ (kg << 4);   // A-read base, even kt
  int ab1 = ab0 ^ 64;                                // odd kt
  int ku2 = c >> 3, e2 = c & 7;
  int wbase = (ku2 * 256 + rgrp * 64 + e2 * 2) ^ ((ku2 & 7) << 4);
  const char* hro = (const char*)hbuf;

  // zero rows 8-15 region
  {
    int buf = tid >> 8, r = tid & 255;
    f16x8 z;
#pragma unroll
    for (int e = 0; e < 8; ++e) z[e] = (_Float16)0.f;
    *(f16x8*)((char*)hbuf + buf * 8192 + (r >> 3) * 256 + 128 + (r & 7) * 16) = z;
  }

  float h_old[4];
#pragma unroll
  for (int rg = 0; rg < 4; ++rg) {
    float hv = ((const float*)hcar)[(bt8 * 8 + rgrp * 4 + rg) * 256 + c];
    h_old[rg] = hv;
    *(_Float16*)((char*)hbuf + (wbase ^ (rg << 4))) = (_Float16)hv;
  }

#pragma unroll
  for (int ii = 0; ii < 4; ++ii) {
    int ix = ii * 512 + tid;
    if (ix < tch * 8) {
      int ti = t0 + (ix >> 3) + 1;
      dnb[ix] = (ti < TT) ? (unsigned char)(dones[ti * BB + bt8 * 8 + (ix & 7)] != 0) : (unsigned char)0;
    }
  }

  const unsigned char* gpt = gi + (size_t)bt16 * 24576 + half * 12288 +
                             (2 * w + blk) * 768 + (u & 31) * 8;
  f16x4 gA[3], gB[3];
#pragma unroll
  for (int g = 0; g < 3; ++g) gA[g] = *(const f16x4*)(gpt + g * 256);

  asm volatile("s_waitcnt lgkmcnt(0)" ::: "memory");
  __builtin_amdgcn_s_barrier();

#define STEP(TL, P, GC, GN)                                                     \
  {                                                                             \
    int tn = (TL) + 1 < tch ? (TL) + 1 : tch - 1;                               \
    const unsigned char* gpn = gpt + (size_t)tn * GSTRIDE;                      \
    GN[0] = *(const f16x4*)(gpn);                                               \
    GN[1] = *(const f16x4*)(gpn + 256);                                         \
    GN[2] = *(const f16x4*)(gpn + 512);                                         \
    f32x4 acc[6];                                                               \
    _Pragma("unroll") for (int jj = 0; jj < 6; ++jj)                            \
        acc[jj] = (f32x4){0.f, 0.f, 0.f, 0.f};                                  \
    _Pragma("unroll") for (int kt = 0; kt < 8; ++kt) {                          \
      f16x8 ah = *(const f16x8*)(hro + (P) * 8192 + kt * 1024 +                 \
                                 ((kt & 1) ? ab1 : ab0));                       \
      _Pragma("unroll") for (int jj = 0; jj < 6; ++jj)                          \
        acc[jj] = __builtin_amdgcn_mfma_f32_16x16x32_f16(ah, whh[jj][kt],       \
                                                         acc[jj], 0, 0, 0);     \
    }                                                                           \
    int dn4 = *(const int*)(dnb + (TL) * 8 + rgrp * 4);                         \
    char* hw = (char*)hbuf + ((P) ^ 1) * 8192;                                  \
    _Pragma("unroll") for (int rg = 0; rg < 4; ++rg) {                          \
      float avr = blk ? acc[3][rg] : acc[0][rg];                                \
      float avz = blk ? acc[4][rg] : acc[1][rg];                                \
      float avn = blk ? acc[5][rg] : acc[2][rg];                                \
      float rs = fsigm((float)GC[0][rg] + avr);                                 \
      float zs = fsigm((float)GC[1][rg] + avz);                                 \
      float ng = ftanh_((float)GC[2][rg] + rs * (avn + bn));                    \
      float hn = ng + zs * (h_old[rg] - ng);                                    \
      hn = ((dn4 >> (rg * 8)) & 0xff) ? 0.f : hn;                               \
      h_old[rg] = hn;                                                           \
      *(_Float16*)(hw + (wbase ^ (rg << 4))) = (_Float16)hn;                    \
    }                                                                           \
    asm volatile("s_waitcnt lgkmcnt(0)" ::: "memory");                          \
    __builtin_amdgcn_s_barrier();                                               \
  }

  for (int tl = 0; tl < tch; tl += 2) {
    STEP(tl, 0, gA, gB);
    STEP(tl + 1, 1, gB, gA);
  }
#undef STEP

#pragma unroll
  for (int rg = 0; rg < 4; ++rg)
    ((float*)hcar)[(bt8 * 8 + rgrp * 4 + rg) * 256 + c] = h_old[rg];

  if (t0 + tch == TT) {
#pragma unroll
    for (int rg = 0; rg < 4; ++rg)
      out[2 * BB * AA + (bt8 * 8 + rgrp * 4 + rg) * 256 + c] = h_old[rg];
    if (tid < 128) {
      int r2 = tid >> 4, a = (tid >> 1) & 7, hd = tid & 1;
      const float* W = hd ? Wsv : Wm;
      float acc2 = 0.f;
      for (int k = 0; k < 256; k += 8) {
        int ku = k >> 3;
        f16x8 vh = *(const f16x8*)(hro + ((ku * 256 + r2 * 16) ^ ((ku & 7) << 4)));
#pragma unroll
        for (int e = 0; e < 8; ++e)
          acc2 += (float)vh[e] * W[a * 256 + k + e];
      }
      int b = bt8 * 8 + r2;
      if (hd == 0) {
        out[b * AA + a] = tanhf(acc2 + bm[a]);
      } else {
        float v = acc2 + bsv[a];
        float sp = fmaxf(v, 0.f) + log1pf(expf(-fabsf(v)));
        out[BB * AA + b * AA + a] = fmaxf(sp, 1e-5f);
      }
    }
  }
}

extern "C" void kernel_launch(void* const* d_in, const int* in_sizes, int n_in,
                              void* d_out, int out_size, void* d_ws, size_t ws_size,
                              hipStream_t stream) {
  const float* x    = (const float*)d_in[0];
  const int*   dn   = (const int*)  d_in[1];
  const float* W1   = (const float*)d_in[2];
  const float* b1   = (const float*)d_in[3];
  const float* W_ih = (const float*)d_in[4];
  const float* W_hh = (const float*)d_in[5];
  const float* b_ih = (const float*)d_in[6];
  const float* b_hh = (const float*)d_in[7];
  const float* Wm   = (const float*)d_in[8];
  const float* bm   = (const float*)d_in[9];
  const float* Wsv  = (const float*)d_in[10];
  const float* bs   = (const float*)d_in[11];
  float* out = (float*)d_out;
  unsigned char* ws = (unsigned char*)d_ws;

  // chunk size: double-buffered gi must fit (round-1 evidence: ws >= 202 MB,
  // so tch=128 [2 x 50.3 MB] is safe); halve defensively if ws smaller.
  int tch = 128;
  while (tch > 2 && (size_t)OFF_GI + 2 * (size_t)tch * 16 * 24576 > ws_size) tch >>= 1;
  size_t GB = (size_t)tch * 16 * 24576;
  int nch = TT / tch;

  prepack<<<200, 256, 0, stream>>>(W1, W_ih, W_hh, ws);
  (void)hipMemsetAsync(ws + OFF_H, 0, 262144, stream);

  // prologue: gi(chunk 0) -> buffer 0
  gru_gi<<<(tch / 2) * 16, 256, 0, stream>>>(x, b1, b_ih, b_hh, ws, ws + OFF_GI, 0);

  for (int i = 0; i < nch; ++i) {
    int t0 = i * tch;
    int last = (i == nch - 1);
    unsigned char* gin  = ws + OFF_GI + (size_t)(i & 1) * GB;
    unsigned char* gout = ws + OFF_GI + (size_t)((i + 1) & 1) * GB;
    int grid = 32 + (last ? 0 : (tch / 2) * 16);
    gru_fused<<<grid, 512, 0, stream>>>(x, dn, b1, b_ih, b_hh, Wm, bm, Wsv, bs,
                                        ws, ws + OFF_H, gin, gout,
                                        t0, tch, t0 + tch, out);
  }
}